// Round 5
// baseline (337.930 us; speedup 1.0000x reference)
//
#include <hip/hip_runtime.h>

#define C_IMG 512
#define C_PT  256
#define IMG_H 48
#define IMG_W 160
#define HWPIX (IMG_H * IMG_W)

#define MP   64     // fallback path tile
#define BK   64
#define SPAD 72

typedef short bf16x8 __attribute__((ext_vector_type(8)));
typedef float f32x4  __attribute__((ext_vector_type(4)));
typedef unsigned u32x4 __attribute__((ext_vector_type(4)));

static __device__ __forceinline__ unsigned short f2bf(float f) {
    unsigned u = __float_as_uint(f);
    u += 0x7fffu + ((u >> 16) & 1u);   // RNE
    return (unsigned short)(u >> 16);
}
static __device__ __forceinline__ unsigned pack2(float lo, float hi) {
    return (unsigned)f2bf(lo) | ((unsigned)f2bf(hi) << 16);
}
// round-half-up variants (2 ops instead of 4; same error bound as RNE)
static __device__ __forceinline__ unsigned short f2bf_hu(float f) {
    return (unsigned short)((__float_as_uint(f) + 0x8000u) >> 16);
}
static __device__ __forceinline__ unsigned pack2_hu(float lo, float hi) {
    return ((__float_as_uint(lo) + 0x8000u) >> 16)
         | ((__float_as_uint(hi) + 0x8000u) & 0xffff0000u);
}
static __device__ __forceinline__ float bflo(unsigned v) { return __uint_as_float(v << 16); }
static __device__ __forceinline__ float bfhi(unsigned v) { return __uint_as_float(v & 0xffff0000u); }

// ---------------- prep: per-point params (blocks < nParamBlk) + align_w cvt ----------------
__global__ __launch_bounds__(256)
void prep_kernel(const float* __restrict__ centers,
                 const float* __restrict__ P2,
                 const float* __restrict__ R0,
                 const float* __restrict__ Tr,
                 const int*   __restrict__ bidx,
                 const float* __restrict__ alw,
                 u32x4* __restrict__ poff,
                 f32x4* __restrict__ pwgt,
                 unsigned short* __restrict__ wbf,
                 int n, int nParamBlk)
{
    if ((int)blockIdx.x >= nParamBlk) {
        // ---- align_w f32 [C_PT][C_IMG] -> bf16 same layout ----
        const int i = (((int)blockIdx.x - nParamBlk) * 256 + (int)threadIdx.x) * 8;
        const float4 a = *(const float4*)(alw + i);
        const float4 b = *(const float4*)(alw + i + 4);
        uint4 o;
        o.x = pack2(a.x, a.y); o.y = pack2(a.z, a.w);
        o.z = pack2(b.x, b.y); o.w = pack2(b.z, b.w);
        *(uint4*)(wbf + i) = o;
        return;
    }
    const int p = blockIdx.x * 256 + threadIdx.x;
    if (p >= n) return;
    const float cx = centers[p * 3 + 0];
    const float cy = centers[p * 3 + 1];
    const float cz = centers[p * 3 + 2];
    const int   b  = bidx[p];
    const float* tr = Tr + b * 16;
    const float c0 = tr[0]*cx + tr[1]*cy + tr[2]*cz + tr[3];
    const float c1 = tr[4]*cx + tr[5]*cy + tr[6]*cz + tr[7];
    const float c2 = tr[8]*cx + tr[9]*cy + tr[10]*cz + tr[11];
    const float c3 = tr[12]*cx + tr[13]*cy + tr[14]*cz + tr[15];
    const float* r0 = R0 + b * 16;
    const float e0 = r0[0]*c0 + r0[1]*c1 + r0[2]*c2 + r0[3]*c3;
    const float e1 = r0[4]*c0 + r0[5]*c1 + r0[6]*c2 + r0[7]*c3;
    const float e2 = r0[8]*c0 + r0[9]*c1 + r0[10]*c2 + r0[11]*c3;
    const float e3 = r0[12]*c0 + r0[13]*c1 + r0[14]*c2 + r0[15]*c3;
    const float* p2 = P2 + b * 12;
    const float ix = p2[0]*e0 + p2[1]*e1 + p2[2]*e2  + p2[3]*e3;
    const float iy = p2[4]*e0 + p2[5]*e1 + p2[6]*e2  + p2[7]*e3;
    const float iz = p2[8]*e0 + p2[9]*e1 + p2[10]*e2 + p2[11]*e3;
    const float depth = fmaxf(iz, 1e-5f);
    const float u = ix / depth;
    const float v = iy / depth;
    const bool valid = (iz > 0.f) && (u >= 0.f) && (u < (float)IMG_W)
                                 && (v >= 0.f) && (v < (float)IMG_H);
    const float x0f = floorf(u), y0f = floorf(v);
    const float wx1 = u - x0f, wx0 = 1.f - wx1;
    const float wy1 = v - y0f, wy0 = 1.f - wy1;
    const float cwv[4] = {wx0 * wy0, wx1 * wy0, wx0 * wy1, wx1 * wy1};
    f32x4 wg; u32x4 of;
    #pragma unroll
    for (int j = 0; j < 4; ++j) {
        const float xf = x0f + (float)(j & 1);
        const float yf = y0f + (float)(j >> 1);
        const bool inb = (xf >= 0.f) && (xf <= (float)(IMG_W - 1))
                      && (yf >= 0.f) && (yf <= (float)(IMG_H - 1));
        const int xc = (int)fminf(fmaxf(xf, 0.f), (float)(IMG_W - 1));
        const int yc = (int)fminf(fmaxf(yf, 0.f), (float)(IMG_H - 1));
        wg[j] = (valid && inb) ? cwv[j] : 0.f;
        of[j] = (unsigned)(((b * IMG_H + yc) * IMG_W + xc) * C_PT);
    }
    poff[p] = of;
    pwgt[p] = wg;
}

// ---------------- per-pixel projection GEMM (bf16-packed transposed LDS tile) ----------------
// PT[b][hw][c_pt] = sum_c img[b][c][hw] * W[c_pt][c]   (bf16 out, f32 acc)
// Block: 64 px x 256 c_pt, 4 waves. Staging packs f32->bf16 ONCE into a
// transposed [px][ch-pair] u32 tile with 128B rows; XOR chunk-swizzle
// (chunk ^= (px&7)^((px>>3)&7)) makes writes 2-way (free) and b128 fragment
// reads a uniform 32-bank partition. A-fragment = ONE ds_read_b128.
__global__ __launch_bounds__(256)
void proj_kernel(const float* __restrict__ img,
                 const unsigned short* __restrict__ wbf,
                 unsigned short* __restrict__ PT)
{
    __shared__ unsigned sT[2][64][32];   // [buf][px][cpair], 128B row pitch
    const int blk  = blockIdx.x;
    const int b    = blk / (HWPIX / 64);
    const int hw0  = (blk % (HWPIX / 64)) * 64;
    const int tid  = threadIdx.x;
    const int lane = tid & 63;
    const int wid  = tid >> 6;
    const int l15  = lane & 15;
    const int quad = lane >> 4;

    // staging: thread owns channel pair (2g, 2g+1), px sub-block [8*sub, 8*sub+8)
    const int g   = tid >> 3;          // 0..31
    const int sub = tid & 7;           // 0..7
    const float* gA = img + (size_t)b * C_IMG * HWPIX + (size_t)(2 * g) * HWPIX + hw0 + sub * 8;

    f32x4 acc[4][4];
    #pragma unroll
    for (int i = 0; i < 4; ++i)
        #pragma unroll
        for (int j = 0; j < 4; ++j)
            acc[i][j] = (f32x4){0.f, 0.f, 0.f, 0.f};

    const unsigned short* bw = wbf + (size_t)(wid * 64 + l15) * C_IMG + quad * 8;

    f32x4 fa0, fa1, fb0, fb1;
    #define STAGE_LOAD(CK) do {                                                     \
        const float* pA = gA + (size_t)((CK) * 64) * HWPIX;                         \
        const float* pB = pA + HWPIX;                                               \
        fa0 = __builtin_nontemporal_load((const f32x4*)pA);                         \
        fa1 = __builtin_nontemporal_load((const f32x4*)(pA + 4));                   \
        fb0 = __builtin_nontemporal_load((const f32x4*)pB);                         \
        fb1 = __builtin_nontemporal_load((const f32x4*)(pB + 4));                   \
    } while (0)
    #define STAGE_COMMIT(BUF) do {                                                 \
        _Pragma("unroll")                                                          \
        for (int i = 0; i < 4; ++i) {                                              \
            const int chk = ((g >> 2) ^ i ^ sub) & 7;                              \
            sT[BUF][sub * 8 + i][(chk << 2) | (g & 3)] = pack2_hu(fa0[i], fb0[i]); \
        }                                                                          \
        _Pragma("unroll")                                                          \
        for (int i = 0; i < 4; ++i) {                                              \
            const int chk = ((g >> 2) ^ (i + 4) ^ sub) & 7;                        \
            sT[BUF][sub * 8 + i + 4][(chk << 2) | (g & 3)] = pack2_hu(fa1[i], fb1[i]); \
        }                                                                          \
    } while (0)

    STAGE_LOAD(0);
    STAGE_COMMIT(0);
    __syncthreads();

    for (int ck = 0; ck < C_IMG / 64; ++ck) {
        const int cur = ck & 1;
        if (ck < C_IMG / 64 - 1) STAGE_LOAD(ck + 1);   // issue early

        #pragma unroll
        for (int kk = 0; kk < 2; ++kk) {
            bf16x8 af[4], bfr[4];
            #pragma unroll
            for (int nt = 0; nt < 4; ++nt)
                bfr[nt] = *(const bf16x8*)(bw + (size_t)(nt * 16) * C_IMG + ck * 64 + kk * 32);
            #pragma unroll
            for (int mt = 0; mt < 4; ++mt) {
                const int px  = mt * 16 + l15;
                const int chk = ((kk * 4 + quad) ^ (px & 7) ^ ((px >> 3) & 7)) & 7;
                af[mt] = *(const bf16x8*)&sT[cur][px][chk << 2];
            }
            #pragma unroll
            for (int mt = 0; mt < 4; ++mt)
                #pragma unroll
                for (int nt = 0; nt < 4; ++nt)
                    acc[mt][nt] = __builtin_amdgcn_mfma_f32_16x16x32_bf16(
                        af[mt], bfr[nt], acc[mt][nt], 0, 0, 0);
        }
        if (ck < C_IMG / 64 - 1) STAGE_COMMIT(cur ^ 1);   // commit late
        __syncthreads();
    }
    #undef STAGE_LOAD
    #undef STAGE_COMMIT

    // epilogue: C/D layout col = l15 (c_pt), row = quad*4 + r (pixel)
    #pragma unroll
    for (int mt = 0; mt < 4; ++mt) {
        #pragma unroll
        for (int r = 0; r < 4; ++r) {
            const int pix = mt * 16 + quad * 4 + r;
            unsigned short* dst = PT + (size_t)(b * HWPIX + hw0 + pix) * C_PT + wid * 64 + l15;
            #pragma unroll
            for (int nt = 0; nt < 4; ++nt)
                dst[nt * 16] = f2bf_hu(acc[mt][nt][r]);
        }
    }
}

// ---------------- per-point bilinear interp in projected (C_PT) space ----------------
// Half-wave per point, 8 ch/lane. Flat-issued loads (clamped indices,
// predicated stores) -> ~24 loads in flight per thread.
__global__ __launch_bounds__(256)
void point_kernel(const float* __restrict__ pf,
                  const unsigned short* __restrict__ PT,
                  const float* __restrict__ alb,
                  const u32x4* __restrict__ poff,
                  const f32x4* __restrict__ pwgt,
                  float* __restrict__ out,
                  int n)
{
    const int tid  = threadIdx.x;
    const int half = tid >> 5;           // 0..7
    const int ch0  = (tid & 31) * 8;     // 8 channels per lane
    const int p0   = blockIdx.x * 32 + half * 4;

    const f32x4 ab0 = *(const f32x4*)(alb + ch0);
    const f32x4 ab1 = *(const f32x4*)(alb + ch0 + 4);

    u32x4 of[4]; f32x4 wg[4];
    #pragma unroll
    for (int it = 0; it < 4; ++it) {
        const int p = min(p0 + it, n - 1);
        of[it] = poff[p];
        wg[it] = pwgt[p];
    }
    u32x4 gv[4][4];
    #pragma unroll
    for (int it = 0; it < 4; ++it)
        #pragma unroll
        for (int j = 0; j < 4; ++j)
            gv[it][j] = *(const u32x4*)(PT + of[it][j] + ch0);

    f32x4 pa[4], pb[4];
    #pragma unroll
    for (int it = 0; it < 4; ++it) {
        const size_t idx = (size_t)min(p0 + it, n - 1) * C_PT + ch0;
        pa[it] = __builtin_nontemporal_load((const f32x4*)(pf + idx));
        pb[it] = __builtin_nontemporal_load((const f32x4*)(pf + idx + 4));
    }

    #pragma unroll
    for (int it = 0; it < 4; ++it) {
        if (p0 + it < n) {
            float s0 = 0.f, s1 = 0.f, s2 = 0.f, s3 = 0.f;
            float s4 = 0.f, s5 = 0.f, s6 = 0.f, s7 = 0.f;
            #pragma unroll
            for (int j = 0; j < 4; ++j) {
                const u32x4 gq = gv[it][j];
                const float w = wg[it][j];
                s0 = fmaf(w, bflo(gq[0]), s0); s1 = fmaf(w, bfhi(gq[0]), s1);
                s2 = fmaf(w, bflo(gq[1]), s2); s3 = fmaf(w, bfhi(gq[1]), s3);
                s4 = fmaf(w, bflo(gq[2]), s4); s5 = fmaf(w, bfhi(gq[2]), s5);
                s6 = fmaf(w, bflo(gq[3]), s6); s7 = fmaf(w, bfhi(gq[3]), s7);
            }
            const size_t idx = (size_t)(p0 + it) * C_PT + ch0;
            f32x4 o0, o1;
            o0[0] = pa[it][0] + ab0[0] + s0;  o0[1] = pa[it][1] + ab0[1] + s1;
            o0[2] = pa[it][2] + ab0[2] + s2;  o0[3] = pa[it][3] + ab0[3] + s3;
            o1[0] = pb[it][0] + ab1[0] + s4;  o1[1] = pb[it][1] + ab1[1] + s5;
            o1[2] = pb[it][2] + ab1[2] + s6;  o1[3] = pb[it][3] + ab1[3] + s7;
            __builtin_nontemporal_store(o0, (f32x4*)(out + idx));
            __builtin_nontemporal_store(o1, (f32x4*)(out + idx + 4));
        }
    }
}

// ---------------- fallback: monolithic single-kernel path (no workspace) ----------------
__global__ __launch_bounds__(256)
void fused_fallback_kernel(const float* __restrict__ pf,
                           const float* __restrict__ centers,
                           const float* __restrict__ img,
                           const float* __restrict__ P2,
                           const float* __restrict__ R0,
                           const float* __restrict__ Tr,
                           const float* __restrict__ alw,
                           const float* __restrict__ alb,
                           const int*   __restrict__ bidx,
                           float* __restrict__ out,
                           int n)
{
    __shared__ float          sWg[MP][4];
    __shared__ int            sOf[MP][4];
    __shared__ unsigned short sS[MP][SPAD];
    __shared__ unsigned short sW[C_PT][SPAD];

    const int tid = threadIdx.x;
    const int pt0 = blockIdx.x * MP;

    if (tid < MP) {
        const int p = pt0 + tid;
        float w[4] = {0.f, 0.f, 0.f, 0.f};
        int   o[4] = {0, 0, 0, 0};
        if (p < n) {
            const float cx = centers[p * 3 + 0];
            const float cy = centers[p * 3 + 1];
            const float cz = centers[p * 3 + 2];
            const int   b  = bidx[p];
            const float* tr = Tr + b * 16;
            const float c0 = tr[0]*cx + tr[1]*cy + tr[2]*cz + tr[3];
            const float c1 = tr[4]*cx + tr[5]*cy + tr[6]*cz + tr[7];
            const float c2 = tr[8]*cx + tr[9]*cy + tr[10]*cz + tr[11];
            const float c3 = tr[12]*cx + tr[13]*cy + tr[14]*cz + tr[15];
            const float* r0 = R0 + b * 16;
            const float e0 = r0[0]*c0 + r0[1]*c1 + r0[2]*c2 + r0[3]*c3;
            const float e1 = r0[4]*c0 + r0[5]*c1 + r0[6]*c2 + r0[7]*c3;
            const float e2 = r0[8]*c0 + r0[9]*c1 + r0[10]*c2 + r0[11]*c3;
            const float e3 = r0[12]*c0 + r0[13]*c1 + r0[14]*c2 + r0[15]*c3;
            const float* p2 = P2 + b * 12;
            const float ix = p2[0]*e0 + p2[1]*e1 + p2[2]*e2  + p2[3]*e3;
            const float iy = p2[4]*e0 + p2[5]*e1 + p2[6]*e2  + p2[7]*e3;
            const float iz = p2[8]*e0 + p2[9]*e1 + p2[10]*e2 + p2[11]*e3;
            const float depth = fmaxf(iz, 1e-5f);
            const float u = ix / depth;
            const float v = iy / depth;
            const bool valid = (iz > 0.f) && (u >= 0.f) && (u < (float)IMG_W)
                                         && (v >= 0.f) && (v < (float)IMG_H);
            const float x0f = floorf(u), y0f = floorf(v);
            const float wx1 = u - x0f, wx0 = 1.f - wx1;
            const float wy1 = v - y0f, wy0 = 1.f - wy1;
            const float cwv[4] = {wx0 * wy0, wx1 * wy0, wx0 * wy1, wx1 * wy1};
            #pragma unroll
            for (int j = 0; j < 4; ++j) {
                const float xf = x0f + (float)(j & 1);
                const float yf = y0f + (float)(j >> 1);
                const bool inb = (xf >= 0.f) && (xf <= (float)(IMG_W - 1))
                              && (yf >= 0.f) && (yf <= (float)(IMG_H - 1));
                const int xc = (int)fminf(fmaxf(xf, 0.f), (float)(IMG_W - 1));
                const int yc = (int)fminf(fmaxf(yf, 0.f), (float)(IMG_H - 1));
                w[j] = (valid && inb) ? cwv[j] : 0.f;
                o[j] = b * C_IMG * HWPIX + yc * IMG_W + xc;
            }
        }
        #pragma unroll
        for (int j = 0; j < 4; ++j) { sWg[tid][j] = w[j]; sOf[tid][j] = o[j]; }
    }

    f32x4 acc[4][4];
    #pragma unroll
    for (int i = 0; i < 4; ++i)
        #pragma unroll
        for (int j = 0; j < 4; ++j)
            acc[i][j] = (f32x4){0.f, 0.f, 0.f, 0.f};

    const int lane = tid & 63;
    const int wid  = tid >> 6;
    const int l15  = lane & 15;
    const int quad = lane >> 4;
    const int sp   = tid >> 2;
    const int ssub = tid & 3;

    __syncthreads();

    for (int ck = 0; ck < C_IMG / BK; ++ck) {
        {
            const float cw0 = sWg[sp][0], cw1 = sWg[sp][1], cw2 = sWg[sp][2], cw3 = sWg[sp][3];
            const int   co0 = sOf[sp][0], co1 = sOf[sp][1], co2 = sOf[sp][2], co3 = sOf[sp][3];
            const int   cb  = ck * BK + ssub * 16;
            const float* ib = img;
            #pragma unroll
            for (int h = 0; h < 2; ++h) {
                uint4 ov;
                unsigned* op = (unsigned*)&ov;
                #pragma unroll
                for (int wI = 0; wI < 4; ++wI) {
                    const int c = cb + h * 8 + 2 * wI;
                    const float vlo = cw0*ib[co0 + c*HWPIX] + cw1*ib[co1 + c*HWPIX]
                                    + cw2*ib[co2 + c*HWPIX] + cw3*ib[co3 + c*HWPIX];
                    const float vhi = cw0*ib[co0 + (c+1)*HWPIX] + cw1*ib[co1 + (c+1)*HWPIX]
                                    + cw2*ib[co2 + (c+1)*HWPIX] + cw3*ib[co3 + (c+1)*HWPIX];
                    op[wI] = pack2(vlo, vhi);
                }
                *(uint4*)&sS[sp][ssub * 16 + h * 8] = ov;
            }
        }
        {
            #pragma unroll
            for (int pass = 0; pass < 4; ++pass) {
                const int r = pass * 64 + (tid >> 2);
                const int c = (tid & 3) * 16;
                const float* wr = alw + (size_t)r * C_IMG + ck * BK + c;
                const float4 f0 = *(const float4*)(wr + 0);
                const float4 f1 = *(const float4*)(wr + 4);
                const float4 f2 = *(const float4*)(wr + 8);
                const float4 f3 = *(const float4*)(wr + 12);
                uint4 oa, ob;
                oa.x = pack2(f0.x, f0.y); oa.y = pack2(f0.z, f0.w);
                oa.z = pack2(f1.x, f1.y); oa.w = pack2(f1.z, f1.w);
                ob.x = pack2(f2.x, f2.y); ob.y = pack2(f2.z, f2.w);
                ob.z = pack2(f3.x, f3.y); ob.w = pack2(f3.z, f3.w);
                *(uint4*)&sW[r][c]     = oa;
                *(uint4*)&sW[r][c + 8] = ob;
            }
        }
        __syncthreads();

        #pragma unroll
        for (int kk = 0; kk < 2; ++kk) {
            bf16x8 af[4], bfr[4];
            #pragma unroll
            for (int mt = 0; mt < 4; ++mt)
                af[mt] = *(const bf16x8*)&sS[mt * 16 + l15][kk * 32 + quad * 8];
            #pragma unroll
            for (int nt = 0; nt < 4; ++nt)
                bfr[nt] = *(const bf16x8*)&sW[wid * 64 + nt * 16 + l15][kk * 32 + quad * 8];
            #pragma unroll
            for (int mt = 0; mt < 4; ++mt)
                #pragma unroll
                for (int nt = 0; nt < 4; ++nt)
                    acc[mt][nt] = __builtin_amdgcn_mfma_f32_16x16x32_bf16(
                        af[mt], bfr[nt], acc[mt][nt], 0, 0, 0);
        }
        __syncthreads();
    }

    #pragma unroll
    for (int mt = 0; mt < 4; ++mt) {
        #pragma unroll
        for (int r = 0; r < 4; ++r) {
            const int p = pt0 + mt * 16 + quad * 4 + r;
            if (p < n) {
                #pragma unroll
                for (int nt = 0; nt < 4; ++nt) {
                    const int nc = wid * 64 + nt * 16 + l15;
                    const size_t idx = (size_t)p * C_PT + nc;
                    out[idx] = pf[idx] + alb[nc] + acc[mt][nt][r];
                }
            }
        }
    }
}

extern "C" void kernel_launch(void* const* d_in, const int* in_sizes, int n_in,
                              void* d_out, int out_size, void* d_ws, size_t ws_size,
                              hipStream_t stream) {
    const float* pf      = (const float*)d_in[0];
    const float* centers = (const float*)d_in[1];
    const float* img     = (const float*)d_in[2];
    const float* P2      = (const float*)d_in[3];
    const float* R0      = (const float*)d_in[4];
    const float* Tr      = (const float*)d_in[5];
    const float* alw     = (const float*)d_in[6];
    const float* alb     = (const float*)d_in[7];
    const int*   bidx    = (const int*)d_in[8];
    float*       out     = (float*)d_out;

    const int n  = in_sizes[8];           // 100000 points
    const int bs = in_sizes[3] / 12;      // P2 is (BS,3,4)

    const size_t tpt = (size_t)bs * HWPIX * C_PT * sizeof(unsigned short);
    const size_t tw  = (size_t)C_PT * C_IMG * sizeof(unsigned short);
    const size_t tof = (size_t)n * 16;
    const size_t twg = (size_t)n * 16;
    if (ws_size >= tpt + tw + tof + twg) {
        unsigned short* PT  = (unsigned short*)d_ws;
        unsigned short* wbf = (unsigned short*)((char*)d_ws + tpt);
        u32x4*          poff = (u32x4*)((char*)d_ws + tpt + tw);
        f32x4*          pwgt = (f32x4*)((char*)d_ws + tpt + tw + tof);

        const int npb = (n + 255) / 256;
        const int ncb = (C_PT * C_IMG / 8) / 256;   // 64
        prep_kernel<<<npb + ncb, 256, 0, stream>>>(
            centers, P2, R0, Tr, bidx, alw, poff, pwgt, wbf, n, npb);
        proj_kernel<<<bs * (HWPIX / 64), 256, 0, stream>>>(img, wbf, PT);
        point_kernel<<<(n + 31) / 32, 256, 0, stream>>>(
            pf, PT, alb, poff, pwgt, out, n);
    } else {
        const int nblk = (n + MP - 1) / MP;
        fused_fallback_kernel<<<nblk, 256, 0, stream>>>(
            pf, centers, img, P2, R0, Tr, alw, alb, bidx, out, n);
    }
}